// Round 14
// baseline (456.978 us; speedup 1.0000x reference)
//
#include <hip/hip_runtime.h>

// ---------------------------------------------------------------------------
// LSTMDecoder: 3 chained LSTM cells + edge FC + 3-head attention + heads.
// B=1024, H=768, S=256, C=(202,183,11).
// R14 = R13 with the nontemporal-load type fixed (ext_vector_type float4;
// the builtin rejects HIP_vector_type). Producer-consumer fusion:
//  - cell3 fused into attn kernel (1024 blocks, launch_bounds(256,4),
//    LDS 36912B -> 4 blocks/CU co-resident; per-row-group flags)
//  - out fused into mid kernel (768 blocks, same handshake)
//  - non-temporal loads on the 805MB attn stream (read-once data)
// fp16 MFMA, counted-vmcnt 4/2/0 64-tile pipeline, fused LSTM epilogues,
// fused coalesced single-pass fp32 attention. 6 kernels + 1 memset.
// ---------------------------------------------------------------------------

typedef unsigned short u16;
typedef _Float16       f16x8 __attribute__((ext_vector_type(8)));
typedef float          f32x4 __attribute__((ext_vector_type(4)));
typedef float          f32x4v __attribute__((ext_vector_type(4)));  // for nontemporal

#define SWZ(r) ((((r) + ((r) >> 2))) & 3)
#define VMCNT(N) asm volatile("s_waitcnt vmcnt(" #N ")" ::: "memory")
#define KBAR()  do { __builtin_amdgcn_s_barrier(); __builtin_amdgcn_sched_barrier(0); } while (0)

__device__ __forceinline__ u16 f2h(float f) {
  _Float16 h = (_Float16)f;
  return __builtin_bit_cast(u16, h);
}
__device__ __forceinline__ float sigm(float x) { return 1.f / (1.f + __expf(-x)); }
__device__ __forceinline__ float ftanh(float x) { return 1.f - 2.f / (__expf(2.f * x) + 1.f); }

__device__ __forceinline__ void gld16(const u16* g, u16* l) {
  __builtin_amdgcn_global_load_lds(
      (const __attribute__((address_space(1))) unsigned int*)(g),
      (__attribute__((address_space(3))) unsigned int*)(l),
      16, 0, 0);
}

// ---- producer/consumer flags (agent scope) --------------------------------
__device__ __forceinline__ void flag_release(unsigned* f) {
  __hip_atomic_fetch_add(f, 1u, __ATOMIC_RELEASE, __HIP_MEMORY_SCOPE_AGENT);
}
__device__ __forceinline__ void flag_wait(unsigned* f, unsigned target) {
  while (__hip_atomic_load(f, __ATOMIC_ACQUIRE, __HIP_MEMORY_SCOPE_AGENT) < target)
    __builtin_amdgcn_s_sleep(2);
}

// ======================= 64-col-N MFMA path ================================
struct KP64 { const u16 *pA, *pW; };

__device__ __forceinline__ void stage64(const KP64& kp, int kt,
                                        u16* Asb, u16* Bsb, int wv) {
  const int off = kt * 32;
  gld16(kp.pA + off, Asb + wv * 512);
  gld16(kp.pW + off, Bsb + wv * 512);
}

__device__ __forceinline__ void compute64(const u16* Asb, const u16* Bsb,
                                          int wv, int frow, int fsl, f32x4* acc) {
  const int ar = wv * 16 + frow;
  f16x8 ah = *(const f16x8*)(Asb + ar * 32 + ((fsl ^ SWZ(ar)) * 8));
  f16x8 bh[4];
#pragma unroll
  for (int n = 0; n < 4; ++n) {
    const int br = n * 16 + frow;
    bh[n] = *(const f16x8*)(Bsb + br * 32 + ((fsl ^ SWZ(br)) * 8));
  }
#pragma unroll
  for (int n = 0; n < 4; ++n)
    acc[n] = __builtin_amdgcn_mfma_f32_16x16x32_f16(ah, bh[n], acc[n], 0, 0, 0);
}

__device__ __forceinline__ void kloop64(const KP64& kp, int NT, u16* As, u16* Bs,
                                        int wv, int frow, int fsl, f32x4* acc) {
  stage64(kp, 0, As,        Bs,        wv);
  stage64(kp, 1, As + 2048, Bs + 2048, wv);
  stage64(kp, 2, As + 4096, Bs + 4096, wv);
  for (int t = 0; t < NT - 2; ++t) {
    VMCNT(4); KBAR();
    const int cb = t & 3;
    compute64(As + cb * 2048, Bs + cb * 2048, wv, frow, fsl, acc);
    if (t + 3 < NT) {
      const int sb = (t + 3) & 3;
      stage64(kp, t + 3, As + sb * 2048, Bs + sb * 2048, wv);
    }
  }
  VMCNT(2); KBAR();
  compute64(As + ((NT - 2) & 3) * 2048, Bs + ((NT - 2) & 3) * 2048,
            wv, frow, fsl, acc);
  VMCNT(0); KBAR();
  compute64(As + ((NT - 1) & 3) * 2048, Bs + ((NT - 1) & 3) * 2048,
            wv, frow, fsl, acc);
}

struct GJob {
  const u16* A; const u16* W;
  float* outf; u16* outh;
  const float* bias; const float* bias2; const float* addend;
  int N; int ldc; int relu;
};

// plain GEMM, 64x64 tile
__device__ __forceinline__ void run_gemm64(const GJob& jb, int bx, int by,
                                           u16* As, u16* Bs, int tid) {
  const int bn0 = bx * 64;
  if (bn0 >= jb.N) return;
  const int bm0 = by * 64;
  const int lane = tid & 63, wv = tid >> 6;
  const int frow = lane & 15, fsl = lane >> 4;

  const int ra = tid >> 2, csa = (tid & 3) ^ SWZ(ra);
  int wr = bn0 + ra; if (wr >= jb.N) wr = jb.N - 1;

  KP64 kp;
  kp.pA = jb.A + (size_t)(bm0 + ra) * 768 + csa * 8;
  kp.pW = jb.W + (size_t)wr * 768 + csa * 8;

  f32x4 acc[4];
#pragma unroll
  for (int n = 0; n < 4; ++n) acc[n] = (f32x4){0.f, 0.f, 0.f, 0.f};

  kloop64(kp, 24, As, Bs, wv, frow, fsl, acc);

  const int rb = (lane >> 4) * 4;
  const int cc = lane & 15;
#pragma unroll
  for (int n = 0; n < 4; ++n) {
    const int col = bn0 + n * 16 + cc;
    if (col >= jb.N) continue;
    float bv = 0.f;
    if (jb.bias)  bv += jb.bias[col];
    if (jb.bias2) bv += jb.bias2[col];
    const int row0 = bm0 + wv * 16 + rb;
#pragma unroll
    for (int r = 0; r < 4; ++r) {
      const int row = row0 + r;
      float v = acc[n][r] + bv;
      if (jb.addend) v += jb.addend[(size_t)row * jb.ldc + col];
      if (jb.relu)   v = fmaxf(v, 0.f);
      if (jb.outf)   jb.outf[(size_t)row * jb.ldc + col] = v;
      if (jb.outh)   jb.outh[(size_t)row * jb.ldc + col] = f2h(v);
    }
  }
}

// LSTM cell, 64 rows x 16 j-cols x 4 gates (B-tile = 64 W-rows).
__device__ __forceinline__ void run_cell64(const u16* A, const u16* W,
                                           const float* bi, const float* bh_,
                                           const float* addend,
                                           const float* cprev,
                                           float* hf, float* cf, u16* hh, u16* ch,
                                           int bx, int by,
                                           u16* As, u16* Bs, int tid) {
  const int bj0 = bx * 16;
  const int bm0 = by * 64;
  const int lane = tid & 63, wv = tid >> 6;
  const int frow = lane & 15, fsl = lane >> 4;

  const int ra = tid >> 2, csa = (tid & 3) ^ SWZ(ra);
  const int wr = (ra >> 4) * 768 + bj0 + (ra & 15);

  KP64 kp;
  kp.pA = A + (size_t)(bm0 + ra) * 768 + csa * 8;
  kp.pW = W + (size_t)wr * 768 + csa * 8;

  f32x4 acc[4];
#pragma unroll
  for (int n = 0; n < 4; ++n) acc[n] = (f32x4){0.f, 0.f, 0.f, 0.f};

  kloop64(kp, 24, As, Bs, wv, frow, fsl, acc);

  const int rb = (lane >> 4) * 4;
  const int cc = lane & 15;
  const int j = bj0 + cc;
  float b_i = 0.f, b_f = 0.f, b_g = 0.f, b_o = 0.f;
  if (bi) {
    b_i = bi[j]        + bh_[j];
    b_f = bi[768 + j]  + bh_[768 + j];
    b_g = bi[1536 + j] + bh_[1536 + j];
    b_o = bi[2304 + j] + bh_[2304 + j];
  }
  const int row0 = bm0 + wv * 16 + rb;
#pragma unroll
  for (int r = 0; r < 4; ++r) {
    const int row = row0 + r;
    float gi = acc[0][r] + b_i;
    float gf = acc[1][r] + b_f;
    float gg = acc[2][r] + b_g;
    float go = acc[3][r] + b_o;
    if (addend) {
      const float* ad = addend + (size_t)row * 6144;
      gi += ad[j]; gf += ad[768 + j]; gg += ad[1536 + j]; go += ad[2304 + j];
    }
    float c = sigm(gi) * ftanh(gg);
    if (cprev) c += sigm(gf) * cprev[row * 768 + j];
    float h = sigm(go) * ftanh(c);
    if (hf) hf[row * 768 + j] = h;
    if (cf) cf[row * 768 + j] = c;
    if (hh) hh[row * 768 + j] = f2h(h);
    if (ch) ch[row * 768 + j] = f2h(c);
  }
}

__device__ __forceinline__ void cvt_seg(const float* s, u16* d, int n4,
                                        int gtid, int nthr) {
  for (int i = gtid; i < n4; i += nthr) {
    float4 v = ((const float4*)s)[i];
    ushort4 h;
    h.x = f2h(v.x); h.y = f2h(v.y); h.z = f2h(v.z); h.w = f2h(v.w);
    ((ushort4*)d)[i] = h;
  }
}

// ---------------------------------------------------------------------------
__global__ __launch_bounds__(256)
void cvt0_k(const float* x, u16* xh, const float* Wih, u16* Wihh)
{
  const int g = blockIdx.x * 256 + threadIdx.x, N = 2048 * 256;
  cvt_seg(x,   xh,   196608,  g, N);
  cvt_seg(Wih, Wihh, 1769472, g, N);
}

// K1: cell1 (0..767) || Gpre task2 (768..1535) || cvt-rest (1536..1919)
struct K1P {
  const u16 *xh, *Wihh;
  const float *bih, *bhh;
  float *h1f, *c1f; u16* h1h;
  float* Gpre;
  const float *Whh, *hfcW, *cfcW, *midW, *o1W, *o2W, *o3W;
  u16 *Whhh, *hfch, *cfch, *midh, *o1h, *o2h, *o3h;
};

__global__ __launch_bounds__(256)
void k1_k(K1P p)
{
  __shared__ __align__(16) u16 As[8192];
  __shared__ __align__(16) u16 Bs[8192];
  const int blk = blockIdx.x, tid = threadIdx.x;

  if (blk < 768) {
    run_cell64(p.xh, p.Wihh, p.bih, p.bhh, nullptr, nullptr,
               p.h1f, p.c1f, p.h1h, nullptr, blk % 48, blk / 48, As, Bs, tid);
  } else if (blk < 1536) {
    const int r = blk - 768;
    GJob jb = { p.xh, p.Wihh + (size_t)3072 * 768, p.Gpre, nullptr,
                p.bih + 3072, p.bhh + 3072, nullptr, 3072, 6144, 0 };
    run_gemm64(jb, r % 48, r / 48, As, Bs, tid);
  } else {
    const int g = (blk - 1536) * 256 + tid, N = 384 * 256;
    cvt_seg(p.Whh + 2359296, p.Whhh, 1179648, g, N);   // Whh[1], Whh[2]
    cvt_seg(p.hfcW, p.hfch, 147456, g, N);
    cvt_seg(p.cfcW, p.cfch, 147456, g, N);
    cvt_seg(p.midW, p.midh, 442368, g, N);
    cvt_seg(p.o1W,  p.o1h,  38784,  g, N);
    cvt_seg(p.o2W,  p.o2h,  35136,  g, N);
    cvt_seg(p.o3W,  p.o3h,  2112,   g, N);
  }
}

// K2: cell2 (0..767) || Gpre task3 (768..1535)
struct K2P {
  const u16 *h1h, *Whhh, *xh, *Wihh;
  const float *Gpre_t2, *c1f, *bih, *bhh;
  float *h2f, *Gpre_t3; u16 *h2h, *c2h;
};

__global__ __launch_bounds__(256)
void k2_k(K2P p)
{
  __shared__ __align__(16) u16 As[8192];
  __shared__ __align__(16) u16 Bs[8192];
  const int blk = blockIdx.x, tid = threadIdx.x;

  if (blk < 768) {
    run_cell64(p.h1h, p.Whhh, nullptr, nullptr, p.Gpre_t2, p.c1f,
               p.h2f, nullptr, p.h2h, p.c2h, blk % 48, blk / 48, As, Bs, tid);
  } else {
    const int r = blk - 768;
    GJob jb = { p.xh, p.Wihh + (size_t)6144 * 768, p.Gpre_t3, nullptr,
                p.bih + 6144, p.bhh + 6144, nullptr, 3072, 6144, 0 };
    run_gemm64(jb, r % 48, r / 48, As, Bs, tid);
  }
}

// K3: hp3/cp3 (z-batched 64-tile GEMMs)
struct GArgs { GJob j[3]; };

__global__ __launch_bounds__(256)
void gemm64_k(GArgs P)
{
  __shared__ __align__(16) u16 As[8192];
  __shared__ __align__(16) u16 Bs[8192];
  run_gemm64(P.j[blockIdx.z], blockIdx.x, blockIdx.y, As, Bs, threadIdx.x);
}

// ---------------------------------------------------------------------------
// K4: cell3 + attention fused via producer-consumer flags.
// 1024 blocks, launch_bounds(256,4), LDS 36912B -> 4 blocks/CU: all blocks
// co-resident => flag spins always make progress. Blocks 0..767 compute one
// cell3 tile then release cnt[by]; every block acquire-waits cnt[row/64]==48
// and runs the single-pass fused attention (nontemporal attn loads).
// ---------------------------------------------------------------------------
struct C3AP {
  const u16 *hp3h, *Whh2h;
  const float *Gpre_t3, *cp3f;
  float* h3f;
  const float *attn, *h1f, *h2f;
  u16 *a1h, *a2h, *a3h;
  unsigned* cnt;                     // [16], zeroed by memset
};

__global__ __launch_bounds__(256, 4)
void c3attn_k(C3AP p)
{
  __shared__ __align__(16) char smem[36912];
  u16* As = (u16*)smem;
  u16* Bs = (u16*)(smem + 16384);
  float* accW  = (float*)smem;            // [4][3][768] flattened
  float* lsumW = (float*)(smem + 36864);  // [12]

  const int blk = blockIdx.x, tid = threadIdx.x;
  const int lane = tid & 63, wv = tid >> 6;

  // ---- producer phase: one cell3 tile ----
  if (blk < 768) {
    run_cell64(p.hp3h, p.Whh2h, nullptr, nullptr, p.Gpre_t3, p.cp3f,
               p.h3f, nullptr, nullptr, nullptr, blk % 48, blk / 48,
               As, Bs, tid);
    __syncthreads();                       // all stores issued; wave-level drain
    if (tid == 0) flag_release(&p.cnt[blk / 48]);
  }

  // ---- consumer phase: attention for batch row b = blk ----
  const int b = blk;
  if (tid == 0) flag_wait(&p.cnt[b >> 6], 48u);
  __syncthreads();                         // h3 visible (acquire done)

  const float* ab = p.attn + (size_t)b * 196608;
  const int cb = lane * 4;

  float4 hh[3][3];
#pragma unroll
  for (int j = 0; j < 3; ++j) {
    hh[0][j] = *(const float4*)(p.h1f + b * 768 + j * 256 + cb);
    hh[1][j] = *(const float4*)(p.h2f + b * 768 + j * 256 + cb);
    hh[2][j] = *(const float4*)(p.h3f + b * 768 + j * 256 + cb);
  }

  float4 acc[3][3];
#pragma unroll
  for (int t3 = 0; t3 < 3; ++t3)
#pragma unroll
    for (int j = 0; j < 3; ++j) acc[t3][j] = (float4){0.f, 0.f, 0.f, 0.f};
  float lsum[3] = {0.f, 0.f, 0.f};

  const int row0 = wv * 64;
  for (int sub = 0; sub < 32; ++sub) {
    const float* rp = ab + (size_t)(row0 + sub * 2) * 768 + cb;
    f32x4v vv[2][3];
#pragma unroll
    for (int s = 0; s < 2; ++s)
#pragma unroll
      for (int j = 0; j < 3; ++j)
        vv[s][j] = __builtin_nontemporal_load(
            (const f32x4v*)(rp + s * 768 + j * 256));

    float q[3][2];
#pragma unroll
    for (int t3 = 0; t3 < 3; ++t3)
#pragma unroll
      for (int s = 0; s < 2; ++s) {
        float d = 0.f;
#pragma unroll
        for (int j = 0; j < 3; ++j) {
          d = fmaf(vv[s][j].x, hh[t3][j].x, d);
          d = fmaf(vv[s][j].y, hh[t3][j].y, d);
          d = fmaf(vv[s][j].z, hh[t3][j].z, d);
          d = fmaf(vv[s][j].w, hh[t3][j].w, d);
        }
        q[t3][s] = d;
      }
#pragma unroll
    for (int t3 = 0; t3 < 3; ++t3)
#pragma unroll
      for (int s = 0; s < 2; ++s) {
#pragma unroll
        for (int d = 1; d < 64; d <<= 1)
          q[t3][s] += __shfl_xor(q[t3][s], d);
        q[t3][s] = __expf(q[t3][s]);
      }
#pragma unroll
    for (int t3 = 0; t3 < 3; ++t3)
#pragma unroll
      for (int s = 0; s < 2; ++s) {
        const float pw = q[t3][s];
        lsum[t3] += pw;
#pragma unroll
        for (int j = 0; j < 3; ++j) {
          acc[t3][j].x = fmaf(pw, vv[s][j].x, acc[t3][j].x);
          acc[t3][j].y = fmaf(pw, vv[s][j].y, acc[t3][j].y);
          acc[t3][j].z = fmaf(pw, vv[s][j].z, acc[t3][j].z);
          acc[t3][j].w = fmaf(pw, vv[s][j].w, acc[t3][j].w);
        }
      }
  }

  __syncthreads();                          // LDS reuse boundary
#pragma unroll
  for (int t3 = 0; t3 < 3; ++t3)
#pragma unroll
    for (int j = 0; j < 3; ++j)
      *(float4*)(&accW[(wv * 3 + t3) * 768 + j * 256 + cb]) = acc[t3][j];
  if (lane == 0) {
#pragma unroll
    for (int t3 = 0; t3 < 3; ++t3) lsumW[wv * 3 + t3] = lsum[t3];
  }
  __syncthreads();

  float ltot[3];
#pragma unroll
  for (int t3 = 0; t3 < 3; ++t3)
    ltot[t3] = lsumW[t3] + lsumW[3 + t3] + lsumW[6 + t3] + lsumW[9 + t3];
  u16* outs[3] = { p.a1h, p.a2h, p.a3h };
#pragma unroll
  for (int cc = 0; cc < 3; ++cc) {
    const int c = tid + cc * 256;
#pragma unroll
    for (int t3 = 0; t3 < 3; ++t3) {
      float s = accW[t3 * 768 + c] + accW[(3 + t3) * 768 + c] +
                accW[(6 + t3) * 768 + c] + accW[(9 + t3) * 768 + c];
      outs[t3][b * 768 + c] = f2h(s / ltot[t3]);
    }
  }
}

// ---------------------------------------------------------------------------
// K5: mid + out fused via flags. 768 blocks: 0..575 mid (release
// cnt2[t*16+by]); 576..767 out (wait cnt2[t*16+by]==12).
// ---------------------------------------------------------------------------
struct HP {
  const u16 *a1h, *a2h, *a3h, *midh, *o1h, *o2h, *o3h;
  const float *midb, *o1b, *o2b, *o3b;
  u16 *m1h, *m2h, *m3h;
  float* out;
  unsigned* cnt2;                    // [48], zeroed by memset
};

__global__ __launch_bounds__(256, 4)
void headso_k(HP p)
{
  __shared__ __align__(16) u16 As[8192];
  __shared__ __align__(16) u16 Bs[8192];
  const int blk = blockIdx.x, tid = threadIdx.x;

  const u16* aIn[3]  = { p.a1h, p.a2h, p.a3h };
  u16*       mOut[3] = { p.m1h, p.m2h, p.m3h };
  const u16* oW[3]   = { p.o1h, p.o2h, p.o3h };
  const float* oB[3] = { p.o1b, p.o2b, p.o3b };
  const int   oN[3]  = { 202, 183, 11 };
  const int   oOff[3] = { 0, 206848, 394240 };

  if (blk < 576) {
    const int t = blk / 192, rem = blk % 192;
    const int by = rem / 12, bx = rem % 12;
    GJob jb = { aIn[t], p.midh + (size_t)t * 589824, nullptr, mOut[t],
                p.midb + t * 768, nullptr, nullptr, 768, 768, 1 };
    run_gemm64(jb, bx, by, As, Bs, tid);
    __syncthreads();
    if (tid == 0) flag_release(&p.cnt2[t * 16 + by]);
  } else {
    const int f = blk - 576;
    const int t = f / 64, rem = f % 64;
    const int by = rem / 4, bx = rem % 4;
    if (tid == 0) flag_wait(&p.cnt2[t * 16 + by], 12u);
    __syncthreads();
    GJob jb = { mOut[t], oW[t], p.out + oOff[t], nullptr,
                oB[t], nullptr, nullptr, oN[t], oN[t], 0 };
    run_gemm64(jb, bx, by, As, Bs, tid);
  }
}

// ---------------------------------------------------------------------------
extern "C" void kernel_launch(void* const* d_in, const int* in_sizes, int n_in,
                              void* d_out, int out_size, void* d_ws, size_t ws_size,
                              hipStream_t stream)
{
  const float* x    = (const float*)d_in[0];
  const float* attn = (const float*)d_in[1];
  const float* Wih  = (const float*)d_in[2];
  const float* Whh  = (const float*)d_in[3];
  const float* bih  = (const float*)d_in[4];
  const float* bhh  = (const float*)d_in[5];
  const float* hfcW = (const float*)d_in[6];
  const float* hfcb = (const float*)d_in[7];
  const float* cfcW = (const float*)d_in[8];
  const float* cfcb = (const float*)d_in[9];
  const float* midW = (const float*)d_in[10];
  const float* midb = (const float*)d_in[11];
  const float* o1W  = (const float*)d_in[12];
  const float* o1b  = (const float*)d_in[13];
  const float* o2W  = (const float*)d_in[14];
  const float* o2b  = (const float*)d_in[15];
  const float* o3W  = (const float*)d_in[16];
  const float* o3b  = (const float*)d_in[17];
  float* out = (float*)d_out;
  char*  ws  = (char*)d_ws;

  float* Gpre = (float*)(ws + 0);               // 1024 x 6144 fp32
  float* h1f  = (float*)(ws + 25165824);
  float* c1f  = (float*)(ws + 28311552);
  float* h2f  = (float*)(ws + 31457280);
  float* cp3f = (float*)(ws + 34603008);
  float* h3f  = (float*)(ws + 37748736);
  u16*   xh   = (u16*)(ws + 40894464);
  u16*   Wihh = (u16*)(ws + 42467328);          // all 3 tasks, 9216x768
  u16*   Whhh = (u16*)(ws + 56623104);          // Whh[1], Whh[2]
  u16*   hfch = (u16*)(ws + 66060288);
  u16*   cfch = (u16*)(ws + 67239936);
  u16*   midh = (u16*)(ws + 68419584);
  u16*   o1h  = (u16*)(ws + 71958528);
  u16*   o2h  = (u16*)(ws + 72268800);
  u16*   o3h  = (u16*)(ws + 72549888);
  u16*   h1h  = (u16*)(ws + 72566784);
  u16*   h2h  = (u16*)(ws + 74139648);
  u16*   c2h  = (u16*)(ws + 75712512);
  u16*   hp3h = (u16*)(ws + 77285376);
  u16*   a1h  = (u16*)(ws + 78858240);
  u16*   a2h  = (u16*)(ws + 80431104);
  u16*   a3h  = (u16*)(ws + 82003968);
  u16*   m1h  = (u16*)(ws + 83576832);
  u16*   m2h  = (u16*)(ws + 85149696);
  u16*   m3h  = (u16*)(ws + 86722560);
  unsigned* cnt1 = (unsigned*)(ws + 88295424);  // [16]
  unsigned* cnt2 = (unsigned*)(ws + 88295488);  // [48]
  // workspace end: 88,295,680 bytes

  // flags must start at 0 every call (ws poisoned once, never re-poisoned)
  (void)hipMemsetAsync(cnt1, 0, 256, stream);

  // ---- K0: cvt x + Wih ----
  cvt0_k<<<2048, 256, 0, stream>>>(x, xh, Wih, Wihh);

  // ---- K1: cell1 || Gpre-task2 || cvt-rest ----
  K1P p1;
  p1.xh = xh; p1.Wihh = Wihh; p1.bih = bih; p1.bhh = bhh;
  p1.h1f = h1f; p1.c1f = c1f; p1.h1h = h1h; p1.Gpre = Gpre;
  p1.Whh = Whh; p1.hfcW = hfcW; p1.cfcW = cfcW; p1.midW = midW;
  p1.o1W = o1W; p1.o2W = o2W; p1.o3W = o3W;
  p1.Whhh = Whhh; p1.hfch = hfch; p1.cfch = cfch; p1.midh = midh;
  p1.o1h = o1h; p1.o2h = o2h; p1.o3h = o3h;
  k1_k<<<1920, 256, 0, stream>>>(p1);

  // ---- K2: cell2 || Gpre-task3 ----
  K2P p2;
  p2.h1h = h1h; p2.Whhh = Whhh; p2.xh = xh; p2.Wihh = Wihh;
  p2.Gpre_t2 = Gpre; p2.c1f = c1f; p2.bih = bih; p2.bhh = bhh;
  p2.h2f = h2f; p2.Gpre_t3 = Gpre + 3072; p2.h2h = h2h; p2.c2h = c2h;
  k2_k<<<1536, 256, 0, stream>>>(p2);

  // ---- K3: hp3 = h1 + h2*hfcW^T + hfcb ; cp3 = c1 + c2*cfcW^T + cfcb ----
  GArgs P;
  P = GArgs{};
  P.j[0] = { h2h, hfch, nullptr, hp3h, hfcb, nullptr, h1f, 768, 768, 0 };
  P.j[1] = { c2h, cfch, cp3f, nullptr, cfcb, nullptr, c1f, 768, 768, 0 };
  P.j[2] = P.j[1];
  gemm64_k<<<dim3(12, 16, 2), 256, 0, stream>>>(P);

  // ---- K4: cell3 + attention (producer-consumer fused) ----
  C3AP p4;
  p4.hp3h = hp3h; p4.Whh2h = Whhh + 2359296;
  p4.Gpre_t3 = Gpre + 3072; p4.cp3f = cp3f; p4.h3f = h3f;
  p4.attn = attn; p4.h1f = h1f; p4.h2f = h2f;
  p4.a1h = a1h; p4.a2h = a2h; p4.a3h = a3h;
  p4.cnt = cnt1;
  c3attn_k<<<1024, 256, 0, stream>>>(p4);

  // ---- K5: mid + out (producer-consumer fused) ----
  HP p5;
  p5.a1h = a1h; p5.a2h = a2h; p5.a3h = a3h; p5.midh = midh;
  p5.o1h = o1h; p5.o2h = o2h; p5.o3h = o3h;
  p5.midb = midb; p5.o1b = o1b; p5.o2b = o2b; p5.o3b = o3b;
  p5.m1h = m1h; p5.m2h = m2h; p5.m3h = m3h;
  p5.out = out; p5.cnt2 = cnt2;
  headso_k<<<768, 256, 0, stream>>>(p5);

  (void)in_sizes; (void)n_in; (void)out_size; (void)ws_size;
}

// Round 15
// 294.281 us; speedup vs baseline: 1.5529x; 1.5529x over previous
//
#include <hip/hip_runtime.h>

// ---------------------------------------------------------------------------
// LSTMDecoder: 3 chained LSTM cells + edge FC + 3-head attention + heads.
// B=1024, H=768, S=256, C=(202,183,11).
// R15 = R12 (295.6us best; R14's flag-fusion regressed 1.5x via cache-
// coherence storms and is abandoned) + fp16 Gpre (gates written/read once;
// halves 50MB of traffic; gate |g|<~3 -> fp16 err ~3e-4, margin holds).
// fp16 MFMA, counted-vmcnt 4/2/0 64-tile pipeline, fused LSTM epilogues,
// fused coalesced single-pass fp32 attention. 8 nodes, no cross-block sync.
// ---------------------------------------------------------------------------

typedef unsigned short u16;
typedef _Float16       f16x8 __attribute__((ext_vector_type(8)));
typedef float          f32x4 __attribute__((ext_vector_type(4)));

#define SWZ(r) ((((r) + ((r) >> 2))) & 3)
#define VMCNT(N) asm volatile("s_waitcnt vmcnt(" #N ")" ::: "memory")
#define KBAR()  do { __builtin_amdgcn_s_barrier(); __builtin_amdgcn_sched_barrier(0); } while (0)

__device__ __forceinline__ u16 f2h(float f) {
  _Float16 h = (_Float16)f;
  return __builtin_bit_cast(u16, h);
}
__device__ __forceinline__ float h2f_(u16 v) {
  return (float)__builtin_bit_cast(_Float16, v);
}
__device__ __forceinline__ float sigm(float x) { return 1.f / (1.f + __expf(-x)); }
__device__ __forceinline__ float ftanh(float x) { return 1.f - 2.f / (__expf(2.f * x) + 1.f); }

__device__ __forceinline__ void gld16(const u16* g, u16* l) {
  __builtin_amdgcn_global_load_lds(
      (const __attribute__((address_space(1))) unsigned int*)(g),
      (__attribute__((address_space(3))) unsigned int*)(l),
      16, 0, 0);
}

// ======================= 64-col-N MFMA path ================================
struct KP64 { const u16 *pA, *pW; };

__device__ __forceinline__ void stage64(const KP64& kp, int kt,
                                        u16* Asb, u16* Bsb, int wv) {
  const int off = kt * 32;
  gld16(kp.pA + off, Asb + wv * 512);
  gld16(kp.pW + off, Bsb + wv * 512);
}

__device__ __forceinline__ void compute64(const u16* Asb, const u16* Bsb,
                                          int wv, int frow, int fsl, f32x4* acc) {
  const int ar = wv * 16 + frow;
  f16x8 ah = *(const f16x8*)(Asb + ar * 32 + ((fsl ^ SWZ(ar)) * 8));
  f16x8 bh[4];
#pragma unroll
  for (int n = 0; n < 4; ++n) {
    const int br = n * 16 + frow;
    bh[n] = *(const f16x8*)(Bsb + br * 32 + ((fsl ^ SWZ(br)) * 8));
  }
#pragma unroll
  for (int n = 0; n < 4; ++n)
    acc[n] = __builtin_amdgcn_mfma_f32_16x16x32_f16(ah, bh[n], acc[n], 0, 0, 0);
}

// 2 loads/thread/tile -> counted vmcnt 4/2/0; 4 buffers of 2048 u16 each side
__device__ __forceinline__ void kloop64(const KP64& kp, int NT, u16* As, u16* Bs,
                                        int wv, int frow, int fsl, f32x4* acc) {
  stage64(kp, 0, As,        Bs,        wv);
  stage64(kp, 1, As + 2048, Bs + 2048, wv);
  stage64(kp, 2, As + 4096, Bs + 4096, wv);
  for (int t = 0; t < NT - 2; ++t) {
    VMCNT(4); KBAR();
    const int cb = t & 3;
    compute64(As + cb * 2048, Bs + cb * 2048, wv, frow, fsl, acc);
    if (t + 3 < NT) {
      const int sb = (t + 3) & 3;
      stage64(kp, t + 3, As + sb * 2048, Bs + sb * 2048, wv);
    }
  }
  VMCNT(2); KBAR();
  compute64(As + ((NT - 2) & 3) * 2048, Bs + ((NT - 2) & 3) * 2048,
            wv, frow, fsl, acc);
  VMCNT(0); KBAR();
  compute64(As + ((NT - 1) & 3) * 2048, Bs + ((NT - 1) & 3) * 2048,
            wv, frow, fsl, acc);
}

struct GJob {
  const u16* A; const u16* W;
  float* outf; u16* outh;
  const float* bias; const float* bias2; const float* addend;
  int N; int ldc; int relu;
};

// plain GEMM, 64x64 tile
__device__ __forceinline__ void run_gemm64(const GJob& jb, int bx, int by,
                                           u16* As, u16* Bs, int tid) {
  const int bn0 = bx * 64;
  if (bn0 >= jb.N) return;
  const int bm0 = by * 64;
  const int lane = tid & 63, wv = tid >> 6;
  const int frow = lane & 15, fsl = lane >> 4;

  const int ra = tid >> 2, csa = (tid & 3) ^ SWZ(ra);
  int wr = bn0 + ra; if (wr >= jb.N) wr = jb.N - 1;

  KP64 kp;
  kp.pA = jb.A + (size_t)(bm0 + ra) * 768 + csa * 8;
  kp.pW = jb.W + (size_t)wr * 768 + csa * 8;

  f32x4 acc[4];
#pragma unroll
  for (int n = 0; n < 4; ++n) acc[n] = (f32x4){0.f, 0.f, 0.f, 0.f};

  kloop64(kp, 24, As, Bs, wv, frow, fsl, acc);

  const int rb = (lane >> 4) * 4;
  const int cc = lane & 15;
#pragma unroll
  for (int n = 0; n < 4; ++n) {
    const int col = bn0 + n * 16 + cc;
    if (col >= jb.N) continue;
    float bv = 0.f;
    if (jb.bias)  bv += jb.bias[col];
    if (jb.bias2) bv += jb.bias2[col];
    const int row0 = bm0 + wv * 16 + rb;
#pragma unroll
    for (int r = 0; r < 4; ++r) {
      const int row = row0 + r;
      float v = acc[n][r] + bv;
      if (jb.addend) v += jb.addend[(size_t)row * jb.ldc + col];
      if (jb.relu)   v = fmaxf(v, 0.f);
      if (jb.outf)   jb.outf[(size_t)row * jb.ldc + col] = v;
      if (jb.outh)   jb.outh[(size_t)row * jb.ldc + col] = f2h(v);
    }
  }
}

// LSTM cell, 64 rows x 16 j-cols x 4 gates (B-tile = 64 W-rows).
// W row for staged B-row r in [0,64): (r>>4)*768 + bj0 + (r&15).
// addend = fp16 Gpre block (row stride 6144, gates at +0/768/1536/2304).
__device__ __forceinline__ void run_cell64(const u16* A, const u16* W,
                                           const float* bi, const float* bh_,
                                           const u16* addend,
                                           const float* cprev,
                                           float* hf, float* cf, u16* hh, u16* ch,
                                           int bx, int by,
                                           u16* As, u16* Bs, int tid) {
  const int bj0 = bx * 16;
  const int bm0 = by * 64;
  const int lane = tid & 63, wv = tid >> 6;
  const int frow = lane & 15, fsl = lane >> 4;

  const int ra = tid >> 2, csa = (tid & 3) ^ SWZ(ra);
  const int wr = (ra >> 4) * 768 + bj0 + (ra & 15);

  KP64 kp;
  kp.pA = A + (size_t)(bm0 + ra) * 768 + csa * 8;
  kp.pW = W + (size_t)wr * 768 + csa * 8;

  f32x4 acc[4];
#pragma unroll
  for (int n = 0; n < 4; ++n) acc[n] = (f32x4){0.f, 0.f, 0.f, 0.f};

  kloop64(kp, 24, As, Bs, wv, frow, fsl, acc);

  const int rb = (lane >> 4) * 4;
  const int cc = lane & 15;
  const int j = bj0 + cc;
  float b_i = 0.f, b_f = 0.f, b_g = 0.f, b_o = 0.f;
  if (bi) {
    b_i = bi[j]        + bh_[j];
    b_f = bi[768 + j]  + bh_[768 + j];
    b_g = bi[1536 + j] + bh_[1536 + j];
    b_o = bi[2304 + j] + bh_[2304 + j];
  }
  const int row0 = bm0 + wv * 16 + rb;
#pragma unroll
  for (int r = 0; r < 4; ++r) {
    const int row = row0 + r;
    float gi = acc[0][r] + b_i;
    float gf = acc[1][r] + b_f;
    float gg = acc[2][r] + b_g;
    float go = acc[3][r] + b_o;
    if (addend) {
      const u16* ad = addend + (size_t)row * 6144;
      gi += h2f_(ad[j]); gf += h2f_(ad[768 + j]);
      gg += h2f_(ad[1536 + j]); go += h2f_(ad[2304 + j]);
    }
    float c = sigm(gi) * ftanh(gg);
    if (cprev) c += sigm(gf) * cprev[row * 768 + j];
    float h = sigm(go) * ftanh(c);
    if (hf) hf[row * 768 + j] = h;
    if (cf) cf[row * 768 + j] = c;
    if (hh) hh[row * 768 + j] = f2h(h);
    if (ch) ch[row * 768 + j] = f2h(c);
  }
}

__device__ __forceinline__ void cvt_seg(const float* s, u16* d, int n4,
                                        int gtid, int nthr) {
  for (int i = gtid; i < n4; i += nthr) {
    float4 v = ((const float4*)s)[i];
    ushort4 h;
    h.x = f2h(v.x); h.y = f2h(v.y); h.z = f2h(v.z); h.w = f2h(v.w);
    ((ushort4*)d)[i] = h;
  }
}

// ---------------------------------------------------------------------------
__global__ __launch_bounds__(256)
void cvt0_k(const float* x, u16* xh, const float* Wih, u16* Wihh)
{
  const int g = blockIdx.x * 256 + threadIdx.x, N = 2048 * 256;
  cvt_seg(x,   xh,   196608,  g, N);
  cvt_seg(Wih, Wihh, 1769472, g, N);
}

// K1: cell1 (0..767) || Gpre task2 (768..1535) || cvt-rest (1536..1919)
struct K1P {
  const u16 *xh, *Wihh;
  const float *bih, *bhh;
  float *h1f, *c1f; u16* h1h;
  u16* Gpre;                                  // fp16 gates, ldc 6144
  const float *Whh, *hfcW, *cfcW, *midW, *o1W, *o2W, *o3W;
  u16 *Whhh, *hfch, *cfch, *midh, *o1h, *o2h, *o3h;
};

__global__ __launch_bounds__(256)
void k1_k(K1P p)
{
  __shared__ __align__(16) u16 As[8192];    // 16 KB
  __shared__ __align__(16) u16 Bs[8192];    // 16 KB -> 32 KB total, 5 blk/CU
  const int blk = blockIdx.x, tid = threadIdx.x;

  if (blk < 768) {
    run_cell64(p.xh, p.Wihh, p.bih, p.bhh, nullptr, nullptr,
               p.h1f, p.c1f, p.h1h, nullptr, blk % 48, blk / 48, As, Bs, tid);
  } else if (blk < 1536) {
    const int r = blk - 768;
    GJob jb = { p.xh, p.Wihh + (size_t)3072 * 768, nullptr, p.Gpre,
                p.bih + 3072, p.bhh + 3072, nullptr, 3072, 6144, 0 };
    run_gemm64(jb, r % 48, r / 48, As, Bs, tid);
  } else {
    const int g = (blk - 1536) * 256 + tid, N = 384 * 256;
    cvt_seg(p.Whh + 2359296, p.Whhh, 1179648, g, N);   // Whh[1], Whh[2]
    cvt_seg(p.hfcW, p.hfch, 147456, g, N);
    cvt_seg(p.cfcW, p.cfch, 147456, g, N);
    cvt_seg(p.midW, p.midh, 442368, g, N);
    cvt_seg(p.o1W,  p.o1h,  38784,  g, N);
    cvt_seg(p.o2W,  p.o2h,  35136,  g, N);
    cvt_seg(p.o3W,  p.o3h,  2112,   g, N);
  }
}

// K2: cell2 (0..767) || Gpre task3 (768..1535)
struct K2P {
  const u16 *h1h, *Whhh, *xh, *Wihh;
  const u16 *Gpre_t2;
  const float *c1f, *bih, *bhh;
  float *h2f; u16 *Gpre_t3, *h2h, *c2h;
};

__global__ __launch_bounds__(256)
void k2_k(K2P p)
{
  __shared__ __align__(16) u16 As[8192];
  __shared__ __align__(16) u16 Bs[8192];
  const int blk = blockIdx.x, tid = threadIdx.x;

  if (blk < 768) {
    run_cell64(p.h1h, p.Whhh, nullptr, nullptr, p.Gpre_t2, p.c1f,
               p.h2f, nullptr, p.h2h, p.c2h, blk % 48, blk / 48, As, Bs, tid);
  } else {
    const int r = blk - 768;
    GJob jb = { p.xh, p.Wihh + (size_t)6144 * 768, nullptr, p.Gpre_t3,
                p.bih + 6144, p.bhh + 6144, nullptr, 3072, 6144, 0 };
    run_gemm64(jb, r % 48, r / 48, As, Bs, tid);
  }
}

// cell3: standalone, 64-tiles, grid (48,16)
__global__ __launch_bounds__(256)
void cell3_k(const u16* __restrict__ A, const u16* __restrict__ W,
             const u16* __restrict__ addend, const float* __restrict__ cprev,
             float* hf)
{
  __shared__ __align__(16) u16 As[8192];
  __shared__ __align__(16) u16 Bs[8192];
  run_cell64(A, W, nullptr, nullptr, addend, cprev, hf, nullptr, nullptr, nullptr,
             blockIdx.x, blockIdx.y, As, Bs, threadIdx.x);
}

// z-batched 64-tile GEMMs (hfc/cfc, mid, out)
struct GArgs { GJob j[3]; };

__global__ __launch_bounds__(256)
void gemm64_k(GArgs P)
{
  __shared__ __align__(16) u16 As[8192];
  __shared__ __align__(16) u16 Bs[8192];
  run_gemm64(P.j[blockIdx.z], blockIdx.x, blockIdx.y, As, Bs, threadIdx.x);
}

// ---------------------------------------------------------------------------
// Fused attention: single pass over attn (805 MB), 3 tasks, coalesced
// lane-owns {256j + 4*lane} cols, wave-local dots, unnormalized exp, one
// end-of-kernel LDS combine. 2-row subtiles + launch_bounds(256,4) ->
// VGPR<=128 -> 4 blocks/CU (R12-verbatim; no flags, no nontemporal).
// ---------------------------------------------------------------------------
__global__ __launch_bounds__(256, 4)
void attn_k(const float* __restrict__ attn,
            const float* __restrict__ h1, const float* __restrict__ h2,
            const float* __restrict__ h3,
            u16* __restrict__ a1, u16* __restrict__ a2, u16* __restrict__ a3)
{
  const int b = blockIdx.x, tid = threadIdx.x;
  const int lane = tid & 63, wv = tid >> 6;
  __shared__ float accW[4][3][768];
  __shared__ float lsumW[4][3];

  const float* ab = attn + (size_t)b * 196608;
  const int cb = lane * 4;

  float4 hh[3][3];
#pragma unroll
  for (int j = 0; j < 3; ++j) {
    hh[0][j] = *(const float4*)(h1 + b * 768 + j * 256 + cb);
    hh[1][j] = *(const float4*)(h2 + b * 768 + j * 256 + cb);
    hh[2][j] = *(const float4*)(h3 + b * 768 + j * 256 + cb);
  }

  float4 acc[3][3];
#pragma unroll
  for (int t3 = 0; t3 < 3; ++t3)
#pragma unroll
    for (int j = 0; j < 3; ++j) acc[t3][j] = (float4){0.f, 0.f, 0.f, 0.f};
  float lsum[3] = {0.f, 0.f, 0.f};

  const int row0 = wv * 64;
  for (int sub = 0; sub < 32; ++sub) {
    const float* rp = ab + (size_t)(row0 + sub * 2) * 768 + cb;
    float4 vv[2][3];
#pragma unroll
    for (int s = 0; s < 2; ++s)
#pragma unroll
      for (int j = 0; j < 3; ++j)
        vv[s][j] = *(const float4*)(rp + s * 768 + j * 256);

    float q[3][2];
#pragma unroll
    for (int t3 = 0; t3 < 3; ++t3)
#pragma unroll
      for (int s = 0; s < 2; ++s) {
        float d = 0.f;
#pragma unroll
        for (int j = 0; j < 3; ++j) {
          d = fmaf(vv[s][j].x, hh[t3][j].x, d);
          d = fmaf(vv[s][j].y, hh[t3][j].y, d);
          d = fmaf(vv[s][j].z, hh[t3][j].z, d);
          d = fmaf(vv[s][j].w, hh[t3][j].w, d);
        }
        q[t3][s] = d;
      }
#pragma unroll
    for (int t3 = 0; t3 < 3; ++t3)
#pragma unroll
      for (int s = 0; s < 2; ++s) {
#pragma unroll
        for (int d = 1; d < 64; d <<= 1)
          q[t3][s] += __shfl_xor(q[t3][s], d);
        q[t3][s] = __expf(q[t3][s]);
      }
#pragma unroll
    for (int t3 = 0; t3 < 3; ++t3)
#pragma unroll
      for (int s = 0; s < 2; ++s) {
        const float pw = q[t3][s];
        lsum[t3] += pw;
#pragma unroll
        for (int j = 0; j < 3; ++j) {
          acc[t3][j].x = fmaf(pw, vv[s][j].x, acc[t3][j].x);
          acc[t3][j].y = fmaf(pw, vv[s][j].y, acc[t3][j].y);
          acc[t3][j].z = fmaf(pw, vv[s][j].z, acc[t3][j].z);
          acc[t3][j].w = fmaf(pw, vv[s][j].w, acc[t3][j].w);
        }
      }
  }

#pragma unroll
  for (int t3 = 0; t3 < 3; ++t3)
#pragma unroll
    for (int j = 0; j < 3; ++j)
      *(float4*)(&accW[wv][t3][j * 256 + cb]) = acc[t3][j];
  if (lane == 0) {
#pragma unroll
    for (int t3 = 0; t3 < 3; ++t3) lsumW[wv][t3] = lsum[t3];
  }
  __syncthreads();

  float ltot[3];
#pragma unroll
  for (int t3 = 0; t3 < 3; ++t3)
    ltot[t3] = lsumW[0][t3] + lsumW[1][t3] + lsumW[2][t3] + lsumW[3][t3];
  u16* outs[3] = { a1, a2, a3 };
#pragma unroll
  for (int cc = 0; cc < 3; ++cc) {
    const int c = tid + cc * 256;
#pragma unroll
    for (int t3 = 0; t3 < 3; ++t3) {
      float s = accW[0][t3][c] + accW[1][t3][c] + accW[2][t3][c] + accW[3][t3][c];
      outs[t3][b * 768 + c] = f2h(s / ltot[t3]);
    }
  }
}

// ---------------------------------------------------------------------------
extern "C" void kernel_launch(void* const* d_in, const int* in_sizes, int n_in,
                              void* d_out, int out_size, void* d_ws, size_t ws_size,
                              hipStream_t stream)
{
  const float* x    = (const float*)d_in[0];
  const float* attn = (const float*)d_in[1];
  const float* Wih  = (const float*)d_in[2];
  const float* Whh  = (const float*)d_in[3];
  const float* bih  = (const float*)d_in[4];
  const float* bhh  = (const float*)d_in[5];
  const float* hfcW = (const float*)d_in[6];
  const float* hfcb = (const float*)d_in[7];
  const float* cfcW = (const float*)d_in[8];
  const float* cfcb = (const float*)d_in[9];
  const float* midW = (const float*)d_in[10];
  const float* midb = (const float*)d_in[11];
  const float* o1W  = (const float*)d_in[12];
  const float* o1b  = (const float*)d_in[13];
  const float* o2W  = (const float*)d_in[14];
  const float* o2b  = (const float*)d_in[15];
  const float* o3W  = (const float*)d_in[16];
  const float* o3b  = (const float*)d_in[17];
  float* out = (float*)d_out;
  char*  ws  = (char*)d_ws;

  u16*   Gpreh = (u16*)(ws + 0);                // 1024 x 6144 fp16 gates
  float* h1f  = (float*)(ws + 25165824);
  float* c1f  = (float*)(ws + 28311552);
  float* h2f  = (float*)(ws + 31457280);
  float* cp3f = (float*)(ws + 34603008);
  float* h3f  = (float*)(ws + 37748736);
  u16*   xh   = (u16*)(ws + 40894464);
  u16*   Wihh = (u16*)(ws + 42467328);          // all 3 tasks, 9216x768
  u16*   Whhh = (u16*)(ws + 56623104);          // Whh[1], Whh[2]
  u16*   hfch = (u16*)(ws + 66060288);
  u16*   cfch = (u16*)(ws + 67239936);
  u16*   midh = (u16*)(ws + 68419584);
  u16*   o1h  = (u16*)(ws + 71958528);
  u16*   o2h  = (u16*)(ws + 72268800);
  u16*   o3h  = (u16*)(ws + 72549888);
  u16*   h1h  = (u16*)(ws + 72566784);
  u16*   h2h  = (u16*)(ws + 74139648);
  u16*   c2h  = (u16*)(ws + 75712512);
  u16*   hp3h = (u16*)(ws + 77285376);
  u16*   a1h  = (u16*)(ws + 78858240);
  u16*   a2h  = (u16*)(ws + 80431104);
  u16*   a3h  = (u16*)(ws + 82003968);
  u16*   m1h  = (u16*)(ws + 83576832);
  u16*   m2h  = (u16*)(ws + 85149696);
  u16*   m3h  = (u16*)(ws + 86722560);
  // workspace end: 88,295,424 bytes

  // ---- K0: cvt x + Wih ----
  cvt0_k<<<2048, 256, 0, stream>>>(x, xh, Wih, Wihh);

  // ---- K1: cell1 || Gpre-task2 || cvt-rest ----
  K1P p1;
  p1.xh = xh; p1.Wihh = Wihh; p1.bih = bih; p1.bhh = bhh;
  p1.h1f = h1f; p1.c1f = c1f; p1.h1h = h1h; p1.Gpre = Gpreh;
  p1.Whh = Whh; p1.hfcW = hfcW; p1.cfcW = cfcW; p1.midW = midW;
  p1.o1W = o1W; p1.o2W = o2W; p1.o3W = o3W;
  p1.Whhh = Whhh; p1.hfch = hfch; p1.cfch = cfch; p1.midh = midh;
  p1.o1h = o1h; p1.o2h = o2h; p1.o3h = o3h;
  k1_k<<<1920, 256, 0, stream>>>(p1);

  // ---- K2: cell2 || Gpre-task3 ----
  K2P p2;
  p2.h1h = h1h; p2.Whhh = Whhh; p2.xh = xh; p2.Wihh = Wihh;
  p2.Gpre_t2 = Gpreh; p2.c1f = c1f; p2.bih = bih; p2.bhh = bhh;
  p2.h2f = h2f; p2.Gpre_t3 = Gpreh + 3072; p2.h2h = h2h; p2.c2h = c2h;
  k2_k<<<1536, 256, 0, stream>>>(p2);

  // ---- K3: hp3 = h1 + h2*hfcW^T + hfcb ; cp3 = c1 + c2*cfcW^T + cfcb ----
  GArgs P;
  P = GArgs{};
  P.j[0] = { h2h, hfch, nullptr, hp3h, hfcb, nullptr, h1f, 768, 768, 0 };
  P.j[1] = { c2h, cfch, cp3f, nullptr, cfcb, nullptr, c1f, 768, 768, 0 };
  P.j[2] = P.j[1];
  gemm64_k<<<dim3(12, 16, 2), 256, 0, stream>>>(P);

  // ---- K4: cell3: gates = Gpre[task3] + hp3*Whh[2]^T ----
  cell3_k<<<dim3(48, 16), 256, 0, stream>>>(hp3h, Whhh + 2359296,
                                            Gpreh + 3072, cp3f, h3f);

  // ---- K5: fused attention ----
  attn_k<<<1024, 256, 0, stream>>>(attn, h1f, h2f, h3f, a1h, a2h, a3h);

  // ---- K6: mid heads ----
  P = GArgs{};
  P.j[0] = { a1h, midh,           nullptr, m1h, midb,        nullptr, nullptr, 768, 768, 1 };
  P.j[1] = { a2h, midh +  589824, nullptr, m2h, midb +  768, nullptr, nullptr, 768, 768, 1 };
  P.j[2] = { a3h, midh + 1179648, nullptr, m3h, midb + 1536, nullptr, nullptr, 768, 768, 1 };
  gemm64_k<<<dim3(12, 16, 3), 256, 0, stream>>>(P);

  // ---- K7: output heads ----
  P = GArgs{};
  P.j[0] = { m1h, o1h, out,          nullptr, o1b, nullptr, nullptr, 202, 202, 0 };
  P.j[1] = { m2h, o2h, out + 206848, nullptr, o2b, nullptr, nullptr, 183, 183, 0 };
  P.j[2] = { m3h, o3h, out + 394240, nullptr, o3b, nullptr, nullptr,  11,  11, 0 };
  gemm64_k<<<dim3(4, 16, 3), 256, 0, stream>>>(P);

  (void)in_sizes; (void)n_in; (void)out_size; (void)ws_size;
}

// Round 16
// 293.547 us; speedup vs baseline: 1.5567x; 1.0025x over previous
//
#include <hip/hip_runtime.h>

// ---------------------------------------------------------------------------
// LSTMDecoder: 3 chained LSTM cells + edge FC + 3-head attention + heads.
// B=1024, H=768, S=256, C=(202,183,11).
// R16 = R15 (294.3us) + node balancing: Gpre3 split across K2/K3 so every
// MFMA node fits one co-residency round (<=1280 blocks at 5 blk/CU):
//   K2 = cell2(768) + Gpre3 cols 0..1535 (384) = 1152
//   K3 = hfc(192) + cfc(192) + Gpre3 cols 1536..3071 (384) = 768
// fp16 MFMA, counted-vmcnt 4/2/0 64-tile pipeline, fused LSTM epilogues,
// fp16 Gpre, fused coalesced single-pass fp32 attention (4 blk/CU). 8 nodes.
// ---------------------------------------------------------------------------

typedef unsigned short u16;
typedef _Float16       f16x8 __attribute__((ext_vector_type(8)));
typedef float          f32x4 __attribute__((ext_vector_type(4)));

#define SWZ(r) ((((r) + ((r) >> 2))) & 3)
#define VMCNT(N) asm volatile("s_waitcnt vmcnt(" #N ")" ::: "memory")
#define KBAR()  do { __builtin_amdgcn_s_barrier(); __builtin_amdgcn_sched_barrier(0); } while (0)

__device__ __forceinline__ u16 f2h(float f) {
  _Float16 h = (_Float16)f;
  return __builtin_bit_cast(u16, h);
}
__device__ __forceinline__ float h2f_(u16 v) {
  return (float)__builtin_bit_cast(_Float16, v);
}
__device__ __forceinline__ float sigm(float x) { return 1.f / (1.f + __expf(-x)); }
__device__ __forceinline__ float ftanh(float x) { return 1.f - 2.f / (__expf(2.f * x) + 1.f); }

__device__ __forceinline__ void gld16(const u16* g, u16* l) {
  __builtin_amdgcn_global_load_lds(
      (const __attribute__((address_space(1))) unsigned int*)(g),
      (__attribute__((address_space(3))) unsigned int*)(l),
      16, 0, 0);
}

// ======================= 64-col-N MFMA path ================================
struct KP64 { const u16 *pA, *pW; };

__device__ __forceinline__ void stage64(const KP64& kp, int kt,
                                        u16* Asb, u16* Bsb, int wv) {
  const int off = kt * 32;
  gld16(kp.pA + off, Asb + wv * 512);
  gld16(kp.pW + off, Bsb + wv * 512);
}

__device__ __forceinline__ void compute64(const u16* Asb, const u16* Bsb,
                                          int wv, int frow, int fsl, f32x4* acc) {
  const int ar = wv * 16 + frow;
  f16x8 ah = *(const f16x8*)(Asb + ar * 32 + ((fsl ^ SWZ(ar)) * 8));
  f16x8 bh[4];
#pragma unroll
  for (int n = 0; n < 4; ++n) {
    const int br = n * 16 + frow;
    bh[n] = *(const f16x8*)(Bsb + br * 32 + ((fsl ^ SWZ(br)) * 8));
  }
#pragma unroll
  for (int n = 0; n < 4; ++n)
    acc[n] = __builtin_amdgcn_mfma_f32_16x16x32_f16(ah, bh[n], acc[n], 0, 0, 0);
}

// 2 loads/thread/tile -> counted vmcnt 4/2/0; 4 buffers of 2048 u16 each side
__device__ __forceinline__ void kloop64(const KP64& kp, int NT, u16* As, u16* Bs,
                                        int wv, int frow, int fsl, f32x4* acc) {
  stage64(kp, 0, As,        Bs,        wv);
  stage64(kp, 1, As + 2048, Bs + 2048, wv);
  stage64(kp, 2, As + 4096, Bs + 4096, wv);
  for (int t = 0; t < NT - 2; ++t) {
    VMCNT(4); KBAR();
    const int cb = t & 3;
    compute64(As + cb * 2048, Bs + cb * 2048, wv, frow, fsl, acc);
    if (t + 3 < NT) {
      const int sb = (t + 3) & 3;
      stage64(kp, t + 3, As + sb * 2048, Bs + sb * 2048, wv);
    }
  }
  VMCNT(2); KBAR();
  compute64(As + ((NT - 2) & 3) * 2048, Bs + ((NT - 2) & 3) * 2048,
            wv, frow, fsl, acc);
  VMCNT(0); KBAR();
  compute64(As + ((NT - 1) & 3) * 2048, Bs + ((NT - 1) & 3) * 2048,
            wv, frow, fsl, acc);
}

struct GJob {
  const u16* A; const u16* W;
  float* outf; u16* outh;
  const float* bias; const float* bias2; const float* addend;
  int N; int ldc; int relu;
};

// plain GEMM, 64x64 tile
__device__ __forceinline__ void run_gemm64(const GJob& jb, int bx, int by,
                                           u16* As, u16* Bs, int tid) {
  const int bn0 = bx * 64;
  if (bn0 >= jb.N) return;
  const int bm0 = by * 64;
  const int lane = tid & 63, wv = tid >> 6;
  const int frow = lane & 15, fsl = lane >> 4;

  const int ra = tid >> 2, csa = (tid & 3) ^ SWZ(ra);
  int wr = bn0 + ra; if (wr >= jb.N) wr = jb.N - 1;

  KP64 kp;
  kp.pA = jb.A + (size_t)(bm0 + ra) * 768 + csa * 8;
  kp.pW = jb.W + (size_t)wr * 768 + csa * 8;

  f32x4 acc[4];
#pragma unroll
  for (int n = 0; n < 4; ++n) acc[n] = (f32x4){0.f, 0.f, 0.f, 0.f};

  kloop64(kp, 24, As, Bs, wv, frow, fsl, acc);

  const int rb = (lane >> 4) * 4;
  const int cc = lane & 15;
#pragma unroll
  for (int n = 0; n < 4; ++n) {
    const int col = bn0 + n * 16 + cc;
    if (col >= jb.N) continue;
    float bv = 0.f;
    if (jb.bias)  bv += jb.bias[col];
    if (jb.bias2) bv += jb.bias2[col];
    const int row0 = bm0 + wv * 16 + rb;
#pragma unroll
    for (int r = 0; r < 4; ++r) {
      const int row = row0 + r;
      float v = acc[n][r] + bv;
      if (jb.addend) v += jb.addend[(size_t)row * jb.ldc + col];
      if (jb.relu)   v = fmaxf(v, 0.f);
      if (jb.outf)   jb.outf[(size_t)row * jb.ldc + col] = v;
      if (jb.outh)   jb.outh[(size_t)row * jb.ldc + col] = f2h(v);
    }
  }
}

// LSTM cell, 64 rows x 16 j-cols x 4 gates (B-tile = 64 W-rows).
// W row for staged B-row r in [0,64): (r>>4)*768 + bj0 + (r&15).
// addend = fp16 Gpre block (row stride 6144, gates at +0/768/1536/2304).
__device__ __forceinline__ void run_cell64(const u16* A, const u16* W,
                                           const float* bi, const float* bh_,
                                           const u16* addend,
                                           const float* cprev,
                                           float* hf, float* cf, u16* hh, u16* ch,
                                           int bx, int by,
                                           u16* As, u16* Bs, int tid) {
  const int bj0 = bx * 16;
  const int bm0 = by * 64;
  const int lane = tid & 63, wv = tid >> 6;
  const int frow = lane & 15, fsl = lane >> 4;

  const int ra = tid >> 2, csa = (tid & 3) ^ SWZ(ra);
  const int wr = (ra >> 4) * 768 + bj0 + (ra & 15);

  KP64 kp;
  kp.pA = A + (size_t)(bm0 + ra) * 768 + csa * 8;
  kp.pW = W + (size_t)wr * 768 + csa * 8;

  f32x4 acc[4];
#pragma unroll
  for (int n = 0; n < 4; ++n) acc[n] = (f32x4){0.f, 0.f, 0.f, 0.f};

  kloop64(kp, 24, As, Bs, wv, frow, fsl, acc);

  const int rb = (lane >> 4) * 4;
  const int cc = lane & 15;
  const int j = bj0 + cc;
  float b_i = 0.f, b_f = 0.f, b_g = 0.f, b_o = 0.f;
  if (bi) {
    b_i = bi[j]        + bh_[j];
    b_f = bi[768 + j]  + bh_[768 + j];
    b_g = bi[1536 + j] + bh_[1536 + j];
    b_o = bi[2304 + j] + bh_[2304 + j];
  }
  const int row0 = bm0 + wv * 16 + rb;
#pragma unroll
  for (int r = 0; r < 4; ++r) {
    const int row = row0 + r;
    float gi = acc[0][r] + b_i;
    float gf = acc[1][r] + b_f;
    float gg = acc[2][r] + b_g;
    float go = acc[3][r] + b_o;
    if (addend) {
      const u16* ad = addend + (size_t)row * 6144;
      gi += h2f_(ad[j]); gf += h2f_(ad[768 + j]);
      gg += h2f_(ad[1536 + j]); go += h2f_(ad[2304 + j]);
    }
    float c = sigm(gi) * ftanh(gg);
    if (cprev) c += sigm(gf) * cprev[row * 768 + j];
    float h = sigm(go) * ftanh(c);
    if (hf) hf[row * 768 + j] = h;
    if (cf) cf[row * 768 + j] = c;
    if (hh) hh[row * 768 + j] = f2h(h);
    if (ch) ch[row * 768 + j] = f2h(c);
  }
}

__device__ __forceinline__ void cvt_seg(const float* s, u16* d, int n4,
                                        int gtid, int nthr) {
  for (int i = gtid; i < n4; i += nthr) {
    float4 v = ((const float4*)s)[i];
    ushort4 h;
    h.x = f2h(v.x); h.y = f2h(v.y); h.z = f2h(v.z); h.w = f2h(v.w);
    ((ushort4*)d)[i] = h;
  }
}

// ---------------------------------------------------------------------------
__global__ __launch_bounds__(256)
void cvt0_k(const float* x, u16* xh, const float* Wih, u16* Wihh)
{
  const int g = blockIdx.x * 256 + threadIdx.x, N = 2048 * 256;
  cvt_seg(x,   xh,   196608,  g, N);
  cvt_seg(Wih, Wihh, 1769472, g, N);
}

// K1: cell1 (0..767) || Gpre task2 (768..1535) || cvt-rest (1536..1919)
struct K1P {
  const u16 *xh, *Wihh;
  const float *bih, *bhh;
  float *h1f, *c1f; u16* h1h;
  u16* Gpre;                                  // fp16 gates, ldc 6144
  const float *Whh, *hfcW, *cfcW, *midW, *o1W, *o2W, *o3W;
  u16 *Whhh, *hfch, *cfch, *midh, *o1h, *o2h, *o3h;
};

__global__ __launch_bounds__(256)
void k1_k(K1P p)
{
  __shared__ __align__(16) u16 As[8192];    // 16 KB
  __shared__ __align__(16) u16 Bs[8192];    // 16 KB -> 32 KB total, 5 blk/CU
  const int blk = blockIdx.x, tid = threadIdx.x;

  if (blk < 768) {
    run_cell64(p.xh, p.Wihh, p.bih, p.bhh, nullptr, nullptr,
               p.h1f, p.c1f, p.h1h, nullptr, blk % 48, blk / 48, As, Bs, tid);
  } else if (blk < 1536) {
    const int r = blk - 768;
    GJob jb = { p.xh, p.Wihh + (size_t)3072 * 768, nullptr, p.Gpre,
                p.bih + 3072, p.bhh + 3072, nullptr, 3072, 6144, 0 };
    run_gemm64(jb, r % 48, r / 48, As, Bs, tid);
  } else {
    const int g = (blk - 1536) * 256 + tid, N = 384 * 256;
    cvt_seg(p.Whh + 2359296, p.Whhh, 1179648, g, N);   // Whh[1], Whh[2]
    cvt_seg(p.hfcW, p.hfch, 147456, g, N);
    cvt_seg(p.cfcW, p.cfch, 147456, g, N);
    cvt_seg(p.midW, p.midh, 442368, g, N);
    cvt_seg(p.o1W,  p.o1h,  38784,  g, N);
    cvt_seg(p.o2W,  p.o2h,  35136,  g, N);
    cvt_seg(p.o3W,  p.o3h,  2112,   g, N);
  }
}

// K2: cell2 (0..767) || Gpre task3 cols 0..1535 (768..1151)  -> 1152 blocks
struct K2P {
  const u16 *h1h, *Whhh, *xh, *Wihh;
  const u16 *Gpre_t2;
  const float *c1f, *bih, *bhh;
  float *h2f; u16 *Gpre_t3, *h2h, *c2h;
};

__global__ __launch_bounds__(256)
void k2_k(K2P p)
{
  __shared__ __align__(16) u16 As[8192];
  __shared__ __align__(16) u16 Bs[8192];
  const int blk = blockIdx.x, tid = threadIdx.x;

  if (blk < 768) {
    run_cell64(p.h1h, p.Whhh, nullptr, nullptr, p.Gpre_t2, p.c1f,
               p.h2f, nullptr, p.h2h, p.c2h, blk % 48, blk / 48, As, Bs, tid);
  } else {
    const int r = blk - 768;                       // 0..383
    GJob jb = { p.xh, p.Wihh + (size_t)6144 * 768, nullptr, p.Gpre_t3,
                p.bih + 6144, p.bhh + 6144, nullptr, 3072, 6144, 0 };
    run_gemm64(jb, r % 24, r / 24, As, Bs, tid);   // bx 0..23 (cols 0..1535)
  }
}

// K3: hfc (0..191) || cfc (192..383) || Gpre task3 cols 1536..3071 (384..767)
struct K3P {
  const u16 *h2h, *hfch, *c2h, *cfch, *xh, *Wihh;
  const float *hfcb, *cfcb, *h1f, *c1f, *bih, *bhh;
  float* cp3f; u16 *hp3h, *Gpre_t3;
};

__global__ __launch_bounds__(256)
void k3_k(K3P p)
{
  __shared__ __align__(16) u16 As[8192];
  __shared__ __align__(16) u16 Bs[8192];
  const int blk = blockIdx.x, tid = threadIdx.x;

  if (blk < 192) {
    GJob jb = { p.h2h, p.hfch, nullptr, p.hp3h, p.hfcb, nullptr, p.h1f,
                768, 768, 0 };
    run_gemm64(jb, blk % 12, blk / 12, As, Bs, tid);
  } else if (blk < 384) {
    const int r = blk - 192;
    GJob jb = { p.c2h, p.cfch, p.cp3f, nullptr, p.cfcb, nullptr, p.c1f,
                768, 768, 0 };
    run_gemm64(jb, r % 12, r / 12, As, Bs, tid);
  } else {
    const int r = blk - 384;                       // 0..383
    GJob jb = { p.xh, p.Wihh + (size_t)6144 * 768, nullptr, p.Gpre_t3,
                p.bih + 6144, p.bhh + 6144, nullptr, 3072, 6144, 0 };
    run_gemm64(jb, 24 + r % 24, r / 24, As, Bs, tid);  // bx 24..47
  }
}

// cell3: standalone, 64-tiles, grid (48,16)
__global__ __launch_bounds__(256)
void cell3_k(const u16* __restrict__ A, const u16* __restrict__ W,
             const u16* __restrict__ addend, const float* __restrict__ cprev,
             float* hf)
{
  __shared__ __align__(16) u16 As[8192];
  __shared__ __align__(16) u16 Bs[8192];
  run_cell64(A, W, nullptr, nullptr, addend, cprev, hf, nullptr, nullptr, nullptr,
             blockIdx.x, blockIdx.y, As, Bs, threadIdx.x);
}

// z-batched 64-tile GEMMs (mid, out)
struct GArgs { GJob j[3]; };

__global__ __launch_bounds__(256)
void gemm64_k(GArgs P)
{
  __shared__ __align__(16) u16 As[8192];
  __shared__ __align__(16) u16 Bs[8192];
  run_gemm64(P.j[blockIdx.z], blockIdx.x, blockIdx.y, As, Bs, threadIdx.x);
}

// ---------------------------------------------------------------------------
// Fused attention: single pass over attn (805 MB), 3 tasks, coalesced
// lane-owns {256j + 4*lane} cols, wave-local dots, unnormalized exp, one
// end-of-kernel LDS combine. 2-row subtiles + launch_bounds(256,4) ->
// VGPR<=128 -> 4 blocks/CU.
// ---------------------------------------------------------------------------
__global__ __launch_bounds__(256, 4)
void attn_k(const float* __restrict__ attn,
            const float* __restrict__ h1, const float* __restrict__ h2,
            const float* __restrict__ h3,
            u16* __restrict__ a1, u16* __restrict__ a2, u16* __restrict__ a3)
{
  const int b = blockIdx.x, tid = threadIdx.x;
  const int lane = tid & 63, wv = tid >> 6;
  __shared__ float accW[4][3][768];
  __shared__ float lsumW[4][3];

  const float* ab = attn + (size_t)b * 196608;
  const int cb = lane * 4;

  float4 hh[3][3];
#pragma unroll
  for (int j = 0; j < 3; ++j) {
    hh[0][j] = *(const float4*)(h1 + b * 768 + j * 256 + cb);
    hh[1][j] = *(const float4*)(h2 + b * 768 + j * 256 + cb);
    hh[2][j] = *(const float4*)(h3 + b * 768 + j * 256 + cb);
  }

  float4 acc[3][3];
#pragma unroll
  for (int t3 = 0; t3 < 3; ++t3)
#pragma unroll
    for (int j = 0; j < 3; ++j) acc[t3][j] = (float4){0.f, 0.f, 0.f, 0.f};
  float lsum[3] = {0.f, 0.f, 0.f};

  const int row0 = wv * 64;
  for (int sub = 0; sub < 32; ++sub) {
    const float* rp = ab + (size_t)(row0 + sub * 2) * 768 + cb;
    float4 vv[2][3];
#pragma unroll
    for (int s = 0; s < 2; ++s)
#pragma unroll
      for (int j = 0; j < 3; ++j)
        vv[s][j] = *(const float4*)(rp + s * 768 + j * 256);

    float q[3][2];
#pragma unroll
    for (int t3 = 0; t3 < 3; ++t3)
#pragma unroll
      for (int s = 0; s < 2; ++s) {
        float d = 0.f;
#pragma unroll
        for (int j = 0; j < 3; ++j) {
          d = fmaf(vv[s][j].x, hh[t3][j].x, d);
          d = fmaf(vv[s][j].y, hh[t3][j].y, d);
          d = fmaf(vv[s][j].z, hh[t3][j].z, d);
          d = fmaf(vv[s][j].w, hh[t3][j].w, d);
        }
        q[t3][s] = d;
      }
#pragma unroll
    for (int t3 = 0; t3 < 3; ++t3)
#pragma unroll
      for (int s = 0; s < 2; ++s) {
#pragma unroll
        for (int d = 1; d < 64; d <<= 1)
          q[t3][s] += __shfl_xor(q[t3][s], d);
        q[t3][s] = __expf(q[t3][s]);
      }
#pragma unroll
    for (int t3 = 0; t3 < 3; ++t3)
#pragma unroll
      for (int s = 0; s < 2; ++s) {
        const float pw = q[t3][s];
        lsum[t3] += pw;
#pragma unroll
        for (int j = 0; j < 3; ++j) {
          acc[t3][j].x = fmaf(pw, vv[s][j].x, acc[t3][j].x);
          acc[t3][j].y = fmaf(pw, vv[s][j].y, acc[t3][j].y);
          acc[t3][j].z = fmaf(pw, vv[s][j].z, acc[t3][j].z);
          acc[t3][j].w = fmaf(pw, vv[s][j].w, acc[t3][j].w);
        }
      }
  }

#pragma unroll
  for (int t3 = 0; t3 < 3; ++t3)
#pragma unroll
    for (int j = 0; j < 3; ++j)
      *(float4*)(&accW[wv][t3][j * 256 + cb]) = acc[t3][j];
  if (lane == 0) {
#pragma unroll
    for (int t3 = 0; t3 < 3; ++t3) lsumW[wv][t3] = lsum[t3];
  }
  __syncthreads();

  float ltot[3];
#pragma unroll
  for (int t3 = 0; t3 < 3; ++t3)
    ltot[t3] = lsumW[0][t3] + lsumW[1][t3] + lsumW[2][t3] + lsumW[3][t3];
  u16* outs[3] = { a1, a2, a3 };
#pragma unroll
  for (int cc = 0; cc < 3; ++cc) {
    const int c = tid + cc * 256;
#pragma unroll
    for (int t3 = 0; t3 < 3; ++t3) {
      float s = accW[0][t3][c] + accW[1][t3][c] + accW[2][t3][c] + accW[3][t3][c];
      outs[t3][b * 768 + c] = f2h(s / ltot[t3]);
    }
  }
}

// ---------------------------------------------------------------------------
extern "C" void kernel_launch(void* const* d_in, const int* in_sizes, int n_in,
                              void* d_out, int out_size, void* d_ws, size_t ws_size,
                              hipStream_t stream)
{
  const float* x    = (const float*)d_in[0];
  const float* attn = (const float*)d_in[1];
  const float* Wih  = (const float*)d_in[2];
  const float* Whh  = (const float*)d_in[3];
  const float* bih  = (const float*)d_in[4];
  const float* bhh  = (const float*)d_in[5];
  const float* hfcW = (const float*)d_in[6];
  const float* hfcb = (const float*)d_in[7];
  const float* cfcW = (const float*)d_in[8];
  const float* cfcb = (const float*)d_in[9];
  const float* midW = (const float*)d_in[10];
  const float* midb = (const float*)d_in[11];
  const float* o1W  = (const float*)d_in[12];
  const float* o1b  = (const float*)d_in[13];
  const float* o2W  = (const float*)d_in[14];
  const float* o2b  = (const float*)d_in[15];
  const float* o3W  = (const float*)d_in[16];
  const float* o3b  = (const float*)d_in[17];
  float* out = (float*)d_out;
  char*  ws  = (char*)d_ws;

  u16*   Gpreh = (u16*)(ws + 0);                // 1024 x 6144 fp16 gates
  float* h1f  = (float*)(ws + 25165824);
  float* c1f  = (float*)(ws + 28311552);
  float* h2f  = (float*)(ws + 31457280);
  float* cp3f = (float*)(ws + 34603008);
  float* h3f  = (float*)(ws + 37748736);
  u16*   xh   = (u16*)(ws + 40894464);
  u16*   Wihh = (u16*)(ws + 42467328);          // all 3 tasks, 9216x768
  u16*   Whhh = (u16*)(ws + 56623104);          // Whh[1], Whh[2]
  u16*   hfch = (u16*)(ws + 66060288);
  u16*   cfch = (u16*)(ws + 67239936);
  u16*   midh = (u16*)(ws + 68419584);
  u16*   o1h  = (u16*)(ws + 71958528);
  u16*   o2h  = (u16*)(ws + 72268800);
  u16*   o3h  = (u16*)(ws + 72549888);
  u16*   h1h  = (u16*)(ws + 72566784);
  u16*   h2h  = (u16*)(ws + 74139648);
  u16*   c2h  = (u16*)(ws + 75712512);
  u16*   hp3h = (u16*)(ws + 77285376);
  u16*   a1h  = (u16*)(ws + 78858240);
  u16*   a2h  = (u16*)(ws + 80431104);
  u16*   a3h  = (u16*)(ws + 82003968);
  u16*   m1h  = (u16*)(ws + 83576832);
  u16*   m2h  = (u16*)(ws + 85149696);
  u16*   m3h  = (u16*)(ws + 86722560);
  // workspace end: 88,295,424 bytes

  // ---- K0: cvt x + Wih ----
  cvt0_k<<<2048, 256, 0, stream>>>(x, xh, Wih, Wihh);

  // ---- K1: cell1 || Gpre-task2 || cvt-rest ----
  K1P p1;
  p1.xh = xh; p1.Wihh = Wihh; p1.bih = bih; p1.bhh = bhh;
  p1.h1f = h1f; p1.c1f = c1f; p1.h1h = h1h; p1.Gpre = Gpreh;
  p1.Whh = Whh; p1.hfcW = hfcW; p1.cfcW = cfcW; p1.midW = midW;
  p1.o1W = o1W; p1.o2W = o2W; p1.o3W = o3W;
  p1.Whhh = Whhh; p1.hfch = hfch; p1.cfch = cfch; p1.midh = midh;
  p1.o1h = o1h; p1.o2h = o2h; p1.o3h = o3h;
  k1_k<<<1920, 256, 0, stream>>>(p1);

  // ---- K2: cell2 || Gpre-task3 (cols 0..1535) ----
  K2P p2;
  p2.h1h = h1h; p2.Whhh = Whhh; p2.xh = xh; p2.Wihh = Wihh;
  p2.Gpre_t2 = Gpreh; p2.c1f = c1f; p2.bih = bih; p2.bhh = bhh;
  p2.h2f = h2f; p2.Gpre_t3 = Gpreh + 3072; p2.h2h = h2h; p2.c2h = c2h;
  k2_k<<<1152, 256, 0, stream>>>(p2);

  // ---- K3: hfc || cfc || Gpre-task3 (cols 1536..3071) ----
  K3P p3;
  p3.h2h = h2h; p3.hfch = hfch; p3.c2h = c2h; p3.cfch = cfch;
  p3.xh = xh; p3.Wihh = Wihh;
  p3.hfcb = hfcb; p3.cfcb = cfcb; p3.h1f = h1f; p3.c1f = c1f;
  p3.bih = bih; p3.bhh = bhh;
  p3.cp3f = cp3f; p3.hp3h = hp3h; p3.Gpre_t3 = Gpreh + 3072;
  k3_k<<<768, 256, 0, stream>>>(p3);

  // ---- K4: cell3: gates = Gpre[task3] + hp3*Whh[2]^T ----
  cell3_k<<<dim3(48, 16), 256, 0, stream>>>(hp3h, Whhh + 2359296,
                                            Gpreh + 3072, cp3f, h3f);

  // ---- K5: fused attention ----
  attn_k<<<1024, 256, 0, stream>>>(attn, h1f, h2f, h3f, a1h, a2h, a3h);

  // ---- K6: mid heads ----
  GArgs P;
  P = GArgs{};
  P.j[0] = { a1h, midh,           nullptr, m1h, midb,        nullptr, nullptr, 768, 768, 1 };
  P.j[1] = { a2h, midh +  589824, nullptr, m2h, midb +  768, nullptr, nullptr, 768, 768, 1 };
  P.j[2] = { a3h, midh + 1179648, nullptr, m3h, midb + 1536, nullptr, nullptr, 768, 768, 1 };
  gemm64_k<<<dim3(12, 16, 3), 256, 0, stream>>>(P);

  // ---- K7: output heads ----
  P = GArgs{};
  P.j[0] = { m1h, o1h, out,          nullptr, o1b, nullptr, nullptr, 202, 202, 0 };
  P.j[1] = { m2h, o2h, out + 206848, nullptr, o2b, nullptr, nullptr, 183, 183, 0 };
  P.j[2] = { m3h, o3h, out + 394240, nullptr, o3b, nullptr, nullptr,  11,  11, 0 };
  gemm64_k<<<dim3(4, 16, 3), 256, 0, stream>>>(P);

  (void)in_sizes; (void)n_in; (void)out_size; (void)ws_size;
}